// Round 3
// baseline (734.108 us; speedup 1.0000x reference)
//
#include <hip/hip_runtime.h>
#include <math.h>

#define HID 1024
#define SEQ 2048
#define VOCAB 50257

// ---------------------------------------------------------------------------
// K0: prep — blocks 0..3: hW[j] = h_last @ attn_W_top[:,j], embedded gather,
//            and zero the context accumulator x[1024..2047].
//            blocks 4.. : gh = W_hh @ h_last + b_hh  (wave per row, 4 rows/block)
// ---------------------------------------------------------------------------
__global__ __launch_bounds__(256) void k_prep(const int* tok, const float* hidden,
                                              const float* attn_W, const float* emb,
                                              const float* W_hh, const float* b_hh,
                                              float* hW, float* gh, float* x) {
    int b = blockIdx.x;
    if (b < 4) {
        int j = b * 256 + threadIdx.x;          // 0..1023
        // embedded -> x[0..1023]; zero context accumulator -> x[1024..2047]
        x[j] = emb[(size_t)tok[0] * HID + j];
        x[1024 + j] = 0.f;
        float acc = 0.f;
#pragma unroll 4
        for (int k = 0; k < HID; ++k)
            acc += hidden[k] * attn_W[(size_t)k * HID + j];   // coalesced over j
        hW[j] = acc;
    } else {
        int wid = threadIdx.x >> 6, lane = threadIdx.x & 63;
        int row = (b - 4) * 4 + wid;            // 0..3071
        const float* wr = W_hh + (size_t)row * HID;
        float acc = 0.f;
#pragma unroll
        for (int it = 0; it < 4; ++it) {
            float4 wv = *(const float4*)(wr + it * 256 + lane * 4);
            float4 hv = *(const float4*)(hidden + it * 256 + lane * 4);
            acc += wv.x * hv.x + wv.y * hv.y + wv.z * hv.z + wv.w * hv.w;
        }
        for (int off = 32; off; off >>= 1) acc += __shfl_down(acc, off);
        if (lane == 0) gh[row] = acc + b_hh[row];
    }
}

// ---------------------------------------------------------------------------
// K1: scores[s] = sum_j tanh(hW[j] + enc[s,:] @ Wbot[:,j]) * attn_v[j]
// 256 blocks, 8 s-rows each, 256 threads: thread owns 4 consecutive j.
// ---------------------------------------------------------------------------
#define TS 8
__global__ __launch_bounds__(256) void k_scores(const float* enc, const float* attn_W,
                                                const float* hW, const float* attn_v,
                                                float* scores) {
    __shared__ float encT[HID][TS];   // 32 KB, [k][ss]
    __shared__ float red[4][TS];
    int s0 = blockIdx.x * TS;
    int tid = threadIdx.x;
    for (int ss = 0; ss < TS; ++ss) {
        const float* er = enc + (size_t)(s0 + ss) * HID;
        for (int k = tid; k < HID; k += 256) encT[k][ss] = er[k];
    }
    __syncthreads();

    int j0 = tid * 4;
    float acc[TS][4];
#pragma unroll
    for (int ss = 0; ss < TS; ++ss)
#pragma unroll
        for (int jj = 0; jj < 4; ++jj) acc[ss][jj] = 0.f;

    const float* Wb = attn_W + (size_t)HID * HID;   // bottom half rows

#define KSTEP(WV, KK) do {                                                   \
        const float* ep = &encT[k + (KK)][0];                                \
        float4 e0 = *(const float4*)(ep);                                    \
        float4 e1 = *(const float4*)(ep + 4);                                \
        float ev[8] = {e0.x, e0.y, e0.z, e0.w, e1.x, e1.y, e1.z, e1.w};      \
        _Pragma("unroll")                                                    \
        for (int ss = 0; ss < TS; ++ss) {                                    \
            float e = ev[ss];                                                \
            acc[ss][0] += e * WV.x;  acc[ss][1] += e * WV.y;                 \
            acc[ss][2] += e * WV.z;  acc[ss][3] += e * WV.w;                 \
        }                                                                    \
    } while (0)

    for (int k = 0; k < HID; k += 4) {
        const float* wp = Wb + (size_t)k * HID + j0;
        float4 w0 = *(const float4*)(wp);
        float4 w1 = *(const float4*)(wp + HID);
        float4 w2 = *(const float4*)(wp + 2 * HID);
        float4 w3 = *(const float4*)(wp + 3 * HID);
        KSTEP(w0, 0); KSTEP(w1, 1); KSTEP(w2, 2); KSTEP(w3, 3);
    }
#undef KSTEP

    float4 hv = *(const float4*)(hW + j0);
    float4 av = *(const float4*)(attn_v + j0);
    int wid = tid >> 6, lane = tid & 63;
#pragma unroll
    for (int ss = 0; ss < TS; ++ss) {
        float p = tanhf(hv.x + acc[ss][0]) * av.x + tanhf(hv.y + acc[ss][1]) * av.y
                + tanhf(hv.z + acc[ss][2]) * av.z + tanhf(hv.w + acc[ss][3]) * av.w;
        for (int off = 32; off; off >>= 1) p += __shfl_down(p, off);
        if (lane == 0) red[wid][ss] = p;
    }
    __syncthreads();
    if (tid < TS)
        scores[s0 + tid] = red[0][tid] + red[1][tid] + red[2][tid] + red[3][tid];
}

// ---------------------------------------------------------------------------
// K2: softmax over 2048 scores -> wts. One block, 1024 threads (2 elems each).
// ---------------------------------------------------------------------------
__global__ __launch_bounds__(1024) void k_softmax(const float* scores, float* wts) {
    __shared__ float red[16];
    int tid = threadIdx.x, wid = tid >> 6, lane = tid & 63;
    float a = scores[tid], b = scores[tid + 1024];
    float m = fmaxf(a, b);
    for (int off = 32; off; off >>= 1) m = fmaxf(m, __shfl_xor(m, off));
    if (lane == 0) red[wid] = m;
    __syncthreads();
    float M = red[0];
#pragma unroll
    for (int q = 1; q < 16; ++q) M = fmaxf(M, red[q]);
    __syncthreads();
    float ea = expf(a - M), eb = expf(b - M);
    float s = ea + eb;
    for (int off = 32; off; off >>= 1) s += __shfl_xor(s, off);
    if (lane == 0) red[wid] = s;
    __syncthreads();
    float S = 0.f;
#pragma unroll
    for (int q = 0; q < 16; ++q) S += red[q];
    float inv = 1.f / S;
    wts[tid] = ea * inv;
    wts[tid + 1024] = eb * inv;
}

// ---------------------------------------------------------------------------
// K3: context[j] = sum_s wts[s]*enc[s][j]  -> x[1024+j]  (atomic partial sums)
// 64 blocks, 32 s-rows each; x[1024..2047] zeroed by k_prep.
// ---------------------------------------------------------------------------
__global__ __launch_bounds__(256) void k_context(const float* enc, const float* wts,
                                                 float* x) {
    int b = blockIdx.x;
    int j0 = threadIdx.x * 4;
    float4 acc = {0.f, 0.f, 0.f, 0.f};
    for (int s = b * 32; s < b * 32 + 32; ++s) {
        float wv = wts[s];
        float4 e = *(const float4*)(enc + (size_t)s * HID + j0);
        acc.x += wv * e.x; acc.y += wv * e.y; acc.z += wv * e.z; acc.w += wv * e.w;
    }
    atomicAdd(&x[1024 + j0 + 0], acc.x);
    atomicAdd(&x[1024 + j0 + 1], acc.y);
    atomicAdd(&x[1024 + j0 + 2], acc.z);
    atomicAdd(&x[1024 + j0 + 3], acc.w);
}

// ---------------------------------------------------------------------------
// K4: gi = W_ih @ x + b_ih.  1536 blocks, 2 rows/block, 2 waves per row (K halves)
// ---------------------------------------------------------------------------
__global__ __launch_bounds__(256) void k_gi(const float* W_ih, const float* b_ih,
                                            const float* x, float* gi) {
    __shared__ float red[4];
    int b = blockIdx.x;
    int wid = threadIdx.x >> 6, lane = threadIdx.x & 63;
    int row = b * 2 + (wid >> 1);
    int half = wid & 1;
    const float* wr = W_ih + (size_t)row * 2048 + half * 1024;
    const float* xr = x + half * 1024;
    float acc = 0.f;
#pragma unroll
    for (int it = 0; it < 4; ++it) {
        float4 wv = *(const float4*)(wr + it * 256 + lane * 4);
        float4 xv = *(const float4*)(xr + it * 256 + lane * 4);
        acc += wv.x * xv.x + wv.y * xv.y + wv.z * xv.z + wv.w * xv.w;
    }
    for (int off = 32; off; off >>= 1) acc += __shfl_down(acc, off);
    if (lane == 0) red[wid] = acc;
    __syncthreads();
    if (threadIdx.x < 2) {
        int r = b * 2 + threadIdx.x;
        gi[r] = red[threadIdx.x * 2] + red[threadIdx.x * 2 + 1] + b_ih[r];
    }
}

// ---------------------------------------------------------------------------
// K5: GRU gate math -> h_new (ws copy + d_out tail)
// ---------------------------------------------------------------------------
__global__ __launch_bounds__(256) void k_gru(const float* gi, const float* gh,
                                             const float* hidden, float* hn,
                                             float* out) {
    int i = blockIdx.x * 256 + threadIdx.x;
    float r = 1.f / (1.f + expf(-(gi[i] + gh[i])));
    float z = 1.f / (1.f + expf(-(gi[1024 + i] + gh[1024 + i])));
    float n = tanhf(gi[2048 + i] + r * gh[2048 + i]);
    float h = (1.f - z) * n + z * hidden[i];
    hn[i] = h;
    out[VOCAB + i] = h;
}

// ---------------------------------------------------------------------------
// K6: logits = out_W @ h_new + out_b; fused per-block (max, sum-exp) partials.
// wave per row, 4 rows/block, 12565 blocks.
// ---------------------------------------------------------------------------
__global__ __launch_bounds__(256) void k_logits(const float* out_W, const float* out_b,
                                                const float* hn, float* logits,
                                                float* pm, float* psum) {
    __shared__ float lg[4];
    int b = blockIdx.x;
    int wid = threadIdx.x >> 6, lane = threadIdx.x & 63;
    int row = b * 4 + wid;
    float logit = -INFINITY;
    if (row < VOCAB) {
        const float* wr = out_W + (size_t)row * HID;
        float acc = 0.f;
#pragma unroll
        for (int it = 0; it < 4; ++it) {
            float4 wv = *(const float4*)(wr + it * 256 + lane * 4);
            float4 hv = *(const float4*)(hn + it * 256 + lane * 4);
            acc += wv.x * hv.x + wv.y * hv.y + wv.z * hv.z + wv.w * hv.w;
        }
        for (int off = 32; off; off >>= 1) acc += __shfl_down(acc, off);
        if (lane == 0) {
            logit = acc + out_b[row];
            logits[row] = logit;
        }
    }
    if (lane == 0) lg[wid] = logit;
    __syncthreads();
    if (threadIdx.x == 0) {
        float m = fmaxf(fmaxf(lg[0], lg[1]), fmaxf(lg[2], lg[3]));
        float s = 0.f;
#pragma unroll
        for (int q = 0; q < 4; ++q)
            if (lg[q] != -INFINITY) s += expf(lg[q] - m);
        pm[b] = m;
        psum[b] = s;
    }
}

// ---------------------------------------------------------------------------
// K7: combine per-block partials -> L = max + log(sum exp)
// ---------------------------------------------------------------------------
__global__ __launch_bounds__(256) void k_combine(const float* pm, const float* psum,
                                                 int n, float* Lval) {
    __shared__ float rm[4], rs[4];
    int tid = threadIdx.x, wid = tid >> 6, lane = tid & 63;
    float m = -INFINITY, s = 0.f;
    for (int i = tid; i < n; i += 256) {
        float bm = pm[i], bs = psum[i];
        float M = fmaxf(m, bm);
        s = s * expf(m - M) + bs * expf(bm - M);
        m = M;
    }
    for (int off = 32; off; off >>= 1) {
        float om = __shfl_xor(m, off), os = __shfl_xor(s, off);
        float M = fmaxf(m, om);
        s = s * expf(m - M) + os * expf(om - M);
        m = M;
    }
    if (lane == 0) { rm[wid] = m; rs[wid] = s; }
    __syncthreads();
    if (tid == 0) {
        float M = fmaxf(fmaxf(rm[0], rm[1]), fmaxf(rm[2], rm[3]));
        float S = rs[0] * expf(rm[0] - M) + rs[1] * expf(rm[1] - M)
                + rs[2] * expf(rm[2] - M) + rs[3] * expf(rm[3] - M);
        Lval[0] = M + logf(S);
    }
}

// ---------------------------------------------------------------------------
// K8: out[i] = logits[i] - L
// ---------------------------------------------------------------------------
__global__ __launch_bounds__(256) void k_final(const float* logits, const float* Lval,
                                               float* out) {
    int i = blockIdx.x * 256 + threadIdx.x;
    if (i < VOCAB) out[i] = logits[i] - Lval[0];
}

extern "C" void kernel_launch(void* const* d_in, const int* in_sizes, int n_in,
                              void* d_out, int out_size, void* d_ws, size_t ws_size,
                              hipStream_t stream) {
    (void)in_sizes; (void)n_in; (void)out_size; (void)ws_size;
    const int*   tok    = (const int*)d_in[0];
    const float* hidden = (const float*)d_in[1];
    const float* enc    = (const float*)d_in[2];
    const float* emb    = (const float*)d_in[3];
    const float* attn_W = (const float*)d_in[4];
    const float* attn_v = (const float*)d_in[5];
    const float* W_ih   = (const float*)d_in[6];
    const float* b_ih   = (const float*)d_in[7];
    const float* W_hh   = (const float*)d_in[8];
    const float* b_hh   = (const float*)d_in[9];
    const float* out_W  = (const float*)d_in[10];
    const float* out_b  = (const float*)d_in[11];
    float* out = (float*)d_out;
    float* ws  = (float*)d_ws;

    // workspace layout (floats)
    float* hW     = ws + 0;       // 1024
    float* gh     = ws + 1024;    // 3072
    float* gi     = ws + 4096;    // 3072
    float* x      = ws + 7168;    // 2048 (embedded | context)
    float* scores = ws + 9216;    // 2048
    float* wts    = ws + 11264;   // 2048
    float* hn     = ws + 13312;   // 1024
    float* logits = ws + 14336;   // 50257 (pad to 50264)
    float* pm     = ws + 64600;   // 12565 (pad to 12568)
    float* psum   = ws + 77168;   // 12565 (pad to 12568)
    float* Lval   = ws + 89736;   // 1

    const int NLOGB = (VOCAB + 3) / 4;  // 12565

    k_prep   <<<4 + 768, 256, 0, stream>>>(tok, hidden, attn_W, emb, W_hh, b_hh, hW, gh, x);
    k_scores <<<SEQ / TS, 256, 0, stream>>>(enc, attn_W, hW, attn_v, scores);
    k_softmax<<<1, 1024, 0, stream>>>(scores, wts);
    k_context<<<64, 256, 0, stream>>>(enc, wts, x);
    k_gi     <<<1536, 256, 0, stream>>>(W_ih, b_ih, x, gi);
    k_gru    <<<4, 256, 0, stream>>>(gi, gh, hidden, hn, out);
    k_logits <<<NLOGB, 256, 0, stream>>>(out_W, out_b, hn, logits, pm, psum);
    k_combine<<<1, 256, 0, stream>>>(pm, psum, NLOGB, Lval);
    k_final  <<<(VOCAB + 255) / 256, 256, 0, stream>>>(logits, Lval, out);
}

// Round 4
// 598.791 us; speedup vs baseline: 1.2260x; 1.2260x over previous
//
#include <hip/hip_runtime.h>
#include <math.h>

#define HID 1024
#define SEQ 2048
#define VOCAB 50257

// ---------------------------------------------------------------------------
// K_init: 1 block. embedded gather -> x[0..1023]; zero x[1024..2047] (context
// accumulator), hW, scores (both atomically accumulated later).
// ---------------------------------------------------------------------------
__global__ __launch_bounds__(256) void k_init(const int* tok, const float* emb,
                                              float* x, float* hW, float* scores) {
    int tid = threadIdx.x;
    size_t ebase = (size_t)tok[0] * HID;
#pragma unroll
    for (int q = 0; q < 4; ++q) {
        int j = q * 256 + tid;
        x[j] = emb[ebase + j];
        x[1024 + j] = 0.f;
        hW[j] = 0.f;
    }
#pragma unroll
    for (int q = 0; q < 8; ++q) scores[q * 256 + tid] = 0.f;
}

// ---------------------------------------------------------------------------
// K_hw: hW[j] += sum_{k in slice} h[k] * attn_W_top[k][j]. 64 blocks x 16 k-rows.
// ---------------------------------------------------------------------------
__global__ __launch_bounds__(256) void k_hw(const float* __restrict__ hidden,
                                            const float* __restrict__ attn_W,
                                            float* hW) {
    int j0 = threadIdx.x * 4;
    int k0 = blockIdx.x * 16;
    float4 acc = {0.f, 0.f, 0.f, 0.f};
#pragma unroll 4
    for (int k = k0; k < k0 + 16; ++k) {
        float h = hidden[k];                                    // uniform -> SGPR
        float4 w = *(const float4*)(attn_W + (size_t)k * HID + j0);
        acc.x += h * w.x; acc.y += h * w.y; acc.z += h * w.z; acc.w += h * w.w;
    }
    atomicAdd(&hW[j0 + 0], acc.x);
    atomicAdd(&hW[j0 + 1], acc.y);
    atomicAdd(&hW[j0 + 2], acc.z);
    atomicAdd(&hW[j0 + 3], acc.w);
}

// ---------------------------------------------------------------------------
// K_gh: gh = W_hh @ h_last + b_hh. 768 blocks, wave per row, 4 rows/block.
// ---------------------------------------------------------------------------
__global__ __launch_bounds__(256) void k_gh(const float* __restrict__ hidden,
                                            const float* __restrict__ W_hh,
                                            const float* __restrict__ b_hh,
                                            float* gh) {
    int wid = threadIdx.x >> 6, lane = threadIdx.x & 63;
    int row = blockIdx.x * 4 + wid;            // 0..3071
    const float* wr = W_hh + (size_t)row * HID;
    float acc = 0.f;
#pragma unroll
    for (int it = 0; it < 4; ++it) {
        float4 wv = *(const float4*)(wr + it * 256 + lane * 4);
        float4 hv = *(const float4*)(hidden + it * 256 + lane * 4);
        acc += wv.x * hv.x + wv.y * hv.y + wv.z * hv.z + wv.w * hv.w;
    }
    for (int off = 32; off; off >>= 1) acc += __shfl_down(acc, off);
    if (lane == 0) gh[row] = acc + b_hh[row];
}

// ---------------------------------------------------------------------------
// K_scores: scores[s] += sum_{j in slice} tanh(hW[j] + enc[s,:]@Wbot[:,j])*v[j]
// Grid = (SEQ/TS) * JSPLIT = 1024 blocks -> 4 blocks/CU (occupancy fix).
// Thread owns ONE j column; enc values are wave-uniform -> scalar loads
// (no LDS at all; old version was LDS-throughput + latency bound).
// ---------------------------------------------------------------------------
#define TS 8
#define JSPLIT 4
__global__ __launch_bounds__(256) void k_scores(const float* __restrict__ enc,
                                                const float* __restrict__ attn_W,
                                                const float* __restrict__ hW,
                                                const float* __restrict__ attn_v,
                                                float* __restrict__ scores) {
    __shared__ float red[4][TS];
    int st = blockIdx.x / JSPLIT;
    int jb = blockIdx.x % JSPLIT;
    int s0 = st * TS;
    int j  = jb * 256 + threadIdx.x;
    const float* __restrict__ Wb   = attn_W + (size_t)HID * HID;  // bottom rows
    const float* __restrict__ erow = enc + (size_t)s0 * HID;

    float acc[TS];
#pragma unroll
    for (int ss = 0; ss < TS; ++ss) acc[ss] = 0.f;

#pragma unroll 4
    for (int k = 0; k < HID; ++k) {
        float w = Wb[(size_t)k * HID + j];       // per-lane, coalesced 256B/wave
#pragma unroll
        for (int ss = 0; ss < TS; ++ss)
            acc[ss] += erow[(size_t)ss * HID + k] * w;   // uniform -> s_load
    }

    float hw = hW[j], v = attn_v[j];
    int wid = threadIdx.x >> 6, lane = threadIdx.x & 63;
#pragma unroll
    for (int ss = 0; ss < TS; ++ss) {
        float p = tanhf(hw + acc[ss]) * v;
        for (int off = 32; off; off >>= 1) p += __shfl_down(p, off);
        if (lane == 0) red[wid][ss] = p;
    }
    __syncthreads();
    if (threadIdx.x < TS)
        atomicAdd(&scores[s0 + threadIdx.x],
                  red[0][threadIdx.x] + red[1][threadIdx.x]
                + red[2][threadIdx.x] + red[3][threadIdx.x]);
}

// ---------------------------------------------------------------------------
// K2: softmax over 2048 scores -> wts. One block, 1024 threads (2 elems each).
// ---------------------------------------------------------------------------
__global__ __launch_bounds__(1024) void k_softmax(const float* scores, float* wts) {
    __shared__ float red[16];
    int tid = threadIdx.x, wid = tid >> 6, lane = tid & 63;
    float a = scores[tid], b = scores[tid + 1024];
    float m = fmaxf(a, b);
    for (int off = 32; off; off >>= 1) m = fmaxf(m, __shfl_xor(m, off));
    if (lane == 0) red[wid] = m;
    __syncthreads();
    float M = red[0];
#pragma unroll
    for (int q = 1; q < 16; ++q) M = fmaxf(M, red[q]);
    __syncthreads();
    float ea = expf(a - M), eb = expf(b - M);
    float s = ea + eb;
    for (int off = 32; off; off >>= 1) s += __shfl_xor(s, off);
    if (lane == 0) red[wid] = s;
    __syncthreads();
    float S = 0.f;
#pragma unroll
    for (int q = 0; q < 16; ++q) S += red[q];
    float inv = 1.f / S;
    wts[tid] = ea * inv;
    wts[tid + 1024] = eb * inv;
}

// ---------------------------------------------------------------------------
// K3: context[j] = sum_s wts[s]*enc[s][j] -> x[1024+j] (atomic partials)
// ---------------------------------------------------------------------------
__global__ __launch_bounds__(256) void k_context(const float* __restrict__ enc,
                                                 const float* __restrict__ wts,
                                                 float* x) {
    int b = blockIdx.x;
    int j0 = threadIdx.x * 4;
    float4 acc = {0.f, 0.f, 0.f, 0.f};
    for (int s = b * 32; s < b * 32 + 32; ++s) {
        float wv = wts[s];                                      // uniform
        float4 e = *(const float4*)(enc + (size_t)s * HID + j0);
        acc.x += wv * e.x; acc.y += wv * e.y; acc.z += wv * e.z; acc.w += wv * e.w;
    }
    atomicAdd(&x[1024 + j0 + 0], acc.x);
    atomicAdd(&x[1024 + j0 + 1], acc.y);
    atomicAdd(&x[1024 + j0 + 2], acc.z);
    atomicAdd(&x[1024 + j0 + 3], acc.w);
}

// ---------------------------------------------------------------------------
// K4: gi = W_ih @ x + b_ih. 1536 blocks, 2 rows/block, 2 waves per row.
// ---------------------------------------------------------------------------
__global__ __launch_bounds__(256) void k_gi(const float* __restrict__ W_ih,
                                            const float* __restrict__ b_ih,
                                            const float* __restrict__ x, float* gi) {
    __shared__ float red[4];
    int b = blockIdx.x;
    int wid = threadIdx.x >> 6, lane = threadIdx.x & 63;
    int row = b * 2 + (wid >> 1);
    int half = wid & 1;
    const float* wr = W_ih + (size_t)row * 2048 + half * 1024;
    const float* xr = x + half * 1024;
    float acc = 0.f;
#pragma unroll
    for (int it = 0; it < 4; ++it) {
        float4 wv = *(const float4*)(wr + it * 256 + lane * 4);
        float4 xv = *(const float4*)(xr + it * 256 + lane * 4);
        acc += wv.x * xv.x + wv.y * xv.y + wv.z * xv.z + wv.w * xv.w;
    }
    for (int off = 32; off; off >>= 1) acc += __shfl_down(acc, off);
    if (lane == 0) red[wid] = acc;
    __syncthreads();
    if (threadIdx.x < 2) {
        int r = b * 2 + threadIdx.x;
        gi[r] = red[threadIdx.x * 2] + red[threadIdx.x * 2 + 1] + b_ih[r];
    }
}

// ---------------------------------------------------------------------------
// K5: GRU gate math -> h_new (ws copy + d_out tail)
// ---------------------------------------------------------------------------
__global__ __launch_bounds__(256) void k_gru(const float* gi, const float* gh,
                                             const float* hidden, float* hn,
                                             float* out) {
    int i = blockIdx.x * 256 + threadIdx.x;
    float r = 1.f / (1.f + expf(-(gi[i] + gh[i])));
    float z = 1.f / (1.f + expf(-(gi[1024 + i] + gh[1024 + i])));
    float n = tanhf(gi[2048 + i] + r * gh[2048 + i]);
    float h = (1.f - z) * n + z * hidden[i];
    hn[i] = h;
    out[VOCAB + i] = h;
}

// ---------------------------------------------------------------------------
// K6: logits = out_W @ h_new + out_b; fused per-block (max, sum-exp) partials.
// ---------------------------------------------------------------------------
__global__ __launch_bounds__(256) void k_logits(const float* __restrict__ out_W,
                                                const float* __restrict__ out_b,
                                                const float* __restrict__ hn,
                                                float* logits, float* pm, float* psum) {
    __shared__ float lg[4];
    int b = blockIdx.x;
    int wid = threadIdx.x >> 6, lane = threadIdx.x & 63;
    int row = b * 4 + wid;
    float logit = -INFINITY;
    if (row < VOCAB) {
        const float* wr = out_W + (size_t)row * HID;
        float acc = 0.f;
#pragma unroll
        for (int it = 0; it < 4; ++it) {
            float4 wv = *(const float4*)(wr + it * 256 + lane * 4);
            float4 hv = *(const float4*)(hn + it * 256 + lane * 4);
            acc += wv.x * hv.x + wv.y * hv.y + wv.z * hv.z + wv.w * hv.w;
        }
        for (int off = 32; off; off >>= 1) acc += __shfl_down(acc, off);
        if (lane == 0) {
            logit = acc + out_b[row];
            logits[row] = logit;
        }
    }
    if (lane == 0) lg[wid] = logit;
    __syncthreads();
    if (threadIdx.x == 0) {
        float m = fmaxf(fmaxf(lg[0], lg[1]), fmaxf(lg[2], lg[3]));
        float s = 0.f;
#pragma unroll
        for (int q = 0; q < 4; ++q)
            if (lg[q] != -INFINITY) s += expf(lg[q] - m);
        pm[b] = m;
        psum[b] = s;
    }
}

// ---------------------------------------------------------------------------
// K7: combine per-block partials -> L = max + log(sum exp)
// ---------------------------------------------------------------------------
__global__ __launch_bounds__(256) void k_combine(const float* pm, const float* psum,
                                                 int n, float* Lval) {
    __shared__ float rm[4], rs[4];
    int tid = threadIdx.x, wid = tid >> 6, lane = tid & 63;
    float m = -INFINITY, s = 0.f;
    for (int i = tid; i < n; i += 256) {
        float bm = pm[i], bs = psum[i];
        float M = fmaxf(m, bm);
        s = s * expf(m - M) + bs * expf(bm - M);
        m = M;
    }
    for (int off = 32; off; off >>= 1) {
        float om = __shfl_xor(m, off), os = __shfl_xor(s, off);
        float M = fmaxf(m, om);
        s = s * expf(m - M) + os * expf(om - M);
        m = M;
    }
    if (lane == 0) { rm[wid] = m; rs[wid] = s; }
    __syncthreads();
    if (tid == 0) {
        float M = fmaxf(fmaxf(rm[0], rm[1]), fmaxf(rm[2], rm[3]));
        float S = rs[0] * expf(rm[0] - M) + rs[1] * expf(rm[1] - M)
                + rs[2] * expf(rm[2] - M) + rs[3] * expf(rm[3] - M);
        Lval[0] = M + logf(S);
    }
}

// ---------------------------------------------------------------------------
// K8: out[i] = logits[i] - L
// ---------------------------------------------------------------------------
__global__ __launch_bounds__(256) void k_final(const float* logits, const float* Lval,
                                               float* out) {
    int i = blockIdx.x * 256 + threadIdx.x;
    if (i < VOCAB) out[i] = logits[i] - Lval[0];
}

extern "C" void kernel_launch(void* const* d_in, const int* in_sizes, int n_in,
                              void* d_out, int out_size, void* d_ws, size_t ws_size,
                              hipStream_t stream) {
    (void)in_sizes; (void)n_in; (void)out_size; (void)ws_size;
    const int*   tok    = (const int*)d_in[0];
    const float* hidden = (const float*)d_in[1];
    const float* enc    = (const float*)d_in[2];
    const float* emb    = (const float*)d_in[3];
    const float* attn_W = (const float*)d_in[4];
    const float* attn_v = (const float*)d_in[5];
    const float* W_ih   = (const float*)d_in[6];
    const float* b_ih   = (const float*)d_in[7];
    const float* W_hh   = (const float*)d_in[8];
    const float* b_hh   = (const float*)d_in[9];
    const float* out_W  = (const float*)d_in[10];
    const float* out_b  = (const float*)d_in[11];
    float* out = (float*)d_out;
    float* ws  = (float*)d_ws;

    // workspace layout (floats)
    float* hW     = ws + 0;       // 1024
    float* gh     = ws + 1024;    // 3072
    float* gi     = ws + 4096;    // 3072
    float* x      = ws + 7168;    // 2048 (embedded | context)
    float* scores = ws + 9216;    // 2048
    float* wts    = ws + 11264;   // 2048
    float* hn     = ws + 13312;   // 1024
    float* logits = ws + 14336;   // 50257 (pad)
    float* pm     = ws + 64600;   // 12565 (pad)
    float* psum   = ws + 77168;   // 12565 (pad)
    float* Lval   = ws + 89736;   // 1

    const int NLOGB = (VOCAB + 3) / 4;  // 12565

    k_init   <<<1, 256, 0, stream>>>(tok, emb, x, hW, scores);
    k_hw     <<<64, 256, 0, stream>>>(hidden, attn_W, hW);
    k_gh     <<<768, 256, 0, stream>>>(hidden, W_hh, b_hh, gh);
    k_scores <<<(SEQ / TS) * JSPLIT, 256, 0, stream>>>(enc, attn_W, hW, attn_v, scores);
    k_softmax<<<1, 1024, 0, stream>>>(scores, wts);
    k_context<<<64, 256, 0, stream>>>(enc, wts, x);
    k_gi     <<<1536, 256, 0, stream>>>(W_ih, b_ih, x, gi);
    k_gru    <<<4, 256, 0, stream>>>(gi, gh, hidden, hn, out);
    k_logits <<<NLOGB, 256, 0, stream>>>(out_W, out_b, hn, logits, pm, psum);
    k_combine<<<1, 256, 0, stream>>>(pm, psum, NLOGB, Lval);
    k_final  <<<(VOCAB + 255) / 256, 256, 0, stream>>>(logits, Lval, out);
}

// Round 6
// 489.550 us; speedup vs baseline: 1.4996x; 1.2231x over previous
//
#include <hip/hip_runtime.h>
#include <math.h>

#define HID 1024
#define SEQ 2048
#define VOCAB 50257

typedef unsigned int  uint;
typedef unsigned short ushort_t;

__device__ __forceinline__ ushort_t f2bf(float f) {   // RNE fp32->bf16
    uint u = __float_as_uint(f);
    uint r = (u + 0x7FFFu + ((u >> 16) & 1u)) >> 16;
    return (ushort_t)r;
}

// ---------------------------------------------------------------------------
// K_init: 1 block. embedded gather -> x[0..1023]; zero x[1024..2047] (context
// acc), hW (k_hw atomics), scores (k_gemm atomics).
// ---------------------------------------------------------------------------
__global__ __launch_bounds__(256) void k_init(const int* tok, const float* emb,
                                              float* x, float* hW, float* scores) {
    int tid = threadIdx.x;
    size_t ebase = (size_t)tok[0] * HID;
#pragma unroll
    for (int q = 0; q < 4; ++q) {
        int j = q * 256 + tid;
        x[j] = emb[ebase + j];
        x[1024 + j] = 0.f;
        hW[j] = 0.f;
    }
#pragma unroll
    for (int q = 0; q < 8; ++q) scores[q * 256 + tid] = 0.f;
}

// ---------------------------------------------------------------------------
// K_hw: hW[j] += sum_{k slice} h[k] * attn_W_top[k][j]. 64 blocks x 16 k-rows.
// ---------------------------------------------------------------------------
__global__ __launch_bounds__(256) void k_hw(const float* __restrict__ hidden,
                                            const float* __restrict__ attn_W,
                                            float* hW) {
    int j0 = threadIdx.x * 4;
    int k0 = blockIdx.x * 16;
    float4 acc = {0.f, 0.f, 0.f, 0.f};
#pragma unroll 4
    for (int k = k0; k < k0 + 16; ++k) {
        float h = hidden[k];                                    // uniform -> SGPR
        float4 w = *(const float4*)(attn_W + (size_t)k * HID + j0);
        acc.x += h * w.x; acc.y += h * w.y; acc.z += h * w.z; acc.w += h * w.w;
    }
    atomicAdd(&hW[j0 + 0], acc.x);
    atomicAdd(&hW[j0 + 1], acc.y);
    atomicAdd(&hW[j0 + 2], acc.z);
    atomicAdd(&hW[j0 + 3], acc.w);
}

// ---------------------------------------------------------------------------
// K_gh: gh = W_hh @ h_last + b_hh. 768 blocks, wave per row, 4 rows/block.
// ---------------------------------------------------------------------------
__global__ __launch_bounds__(256) void k_gh(const float* __restrict__ hidden,
                                            const float* __restrict__ W_hh,
                                            const float* __restrict__ b_hh,
                                            float* gh) {
    int wid = threadIdx.x >> 6, lane = threadIdx.x & 63;
    int row = blockIdx.x * 4 + wid;            // 0..3071
    const float* wr = W_hh + (size_t)row * HID;
    float acc = 0.f;
#pragma unroll
    for (int it = 0; it < 4; ++it) {
        float4 wv = *(const float4*)(wr + it * 256 + lane * 4);
        float4 hv = *(const float4*)(hidden + it * 256 + lane * 4);
        acc += wv.x * hv.x + wv.y * hv.y + wv.z * hv.z + wv.w * hv.w;
    }
    for (int off = 32; off; off >>= 1) acc += __shfl_down(acc, off);
    if (lane == 0) gh[row] = acc + b_hh[row];
}

// ---------------------------------------------------------------------------
// K_transW: one-time transpose+convert of Wbot (attn_W rows 1024..2047) into
// WT[j][k] bf16, so GEMM B-fragments read contiguous k. 256 blocks, 64x64 tile.
// ---------------------------------------------------------------------------
__global__ __launch_bounds__(256) void k_transW(const float* __restrict__ attn_W,
                                                ushort_t* __restrict__ WT) {
    __shared__ ushort_t T[64][68];        // pad 4 ushorts
    const float* Wb = attn_W + (size_t)HID * HID;
    int bx = blockIdx.x & 15;             // j-tile
    int by = blockIdx.x >> 4;             // k-tile
    int j0 = bx * 64, k0 = by * 64;
    int t = threadIdx.x;
    int kk = t >> 4;                      // 0..15
    int jj = (t & 15) * 4;                // 0..60
#pragma unroll
    for (int p = 0; p < 4; ++p) {
        int k = kk + p * 16;
        float4 wv = *(const float4*)(Wb + (size_t)(k0 + k) * HID + j0 + jj);
        ushort4 u;
        u.x = f2bf(wv.x); u.y = f2bf(wv.y); u.z = f2bf(wv.z); u.w = f2bf(wv.w);
        *(ushort4*)&T[k][jj] = u;
    }
    __syncthreads();
    int j = t >> 2, g = t & 3;
#pragma unroll
    for (int half = 0; half < 2; ++half) {
        int kc = g * 8 + half * 32;
        ushort_t tmp[8];
#pragma unroll
        for (int e = 0; e < 8; ++e) tmp[e] = T[kc + e][j];
        uint4 o;
        o.x = (uint)tmp[0] | ((uint)tmp[1] << 16);
        o.y = (uint)tmp[2] | ((uint)tmp[3] << 16);
        o.z = (uint)tmp[4] | ((uint)tmp[5] << 16);
        o.w = (uint)tmp[6] | ((uint)tmp[7] << 16);
        *(uint4*)(WT + (size_t)(j0 + j) * HID + k0 + kc) = o;
    }
}

// ---------------------------------------------------------------------------
// K_gemm: scores via MFMA. T = enc @ Wbot in bf16 (enc converted on the fly),
// fused epilogue tanh(hW+T)*v reduced over j, atomicAdd into scores.
// Grid 512 = 32 s-tiles x 16 j-tiles. 64x64 tile, BK=32, 4 waves.
// ---------------------------------------------------------------------------
typedef __attribute__((ext_vector_type(8))) short bf16x8;
typedef __attribute__((ext_vector_type(4))) float f32x4;

__global__ __launch_bounds__(256) void k_gemm(const float* __restrict__ enc,
                                              const ushort_t* __restrict__ WT,
                                              const float* __restrict__ hW,
                                              const float* __restrict__ attn_v,
                                              float* __restrict__ scores) {
    __shared__ ushort_t As[64][40];      // 64 s-rows x 32 k (+8 pad)
    __shared__ ushort_t Bs[64][40];      // 64 j-rows x 32 k (+8 pad)
    int bj = blockIdx.x & 15;
    int bs = blockIdx.x >> 4;
    int s0 = bs * 64, j0 = bj * 64;
    int t = threadIdx.x, l = t & 63, w = t >> 6;
    int sr = t >> 2;                     // staging row 0..63
    int sp = (t & 3) * 8;                // k-part 0,8,16,24
    int cl = l & 15;                     // column lane within 16
    int kq = l >> 4;                     // k-quarter 0..3
    int ac = kq * 8;

    f32x4 acc0 = {0,0,0,0}, acc1 = {0,0,0,0}, acc2 = {0,0,0,0}, acc3 = {0,0,0,0};

    for (int ks = 0; ks < HID / 32; ++ks) {
        int k0 = ks * 32;
        // stage A: enc fp32 -> bf16
        const float* ap = enc + (size_t)(s0 + sr) * HID + k0 + sp;
        float4 a0 = *(const float4*)(ap);
        float4 a1 = *(const float4*)(ap + 4);
        uint4 ua;
        ua.x = (uint)f2bf(a0.x) | ((uint)f2bf(a0.y) << 16);
        ua.y = (uint)f2bf(a0.z) | ((uint)f2bf(a0.w) << 16);
        ua.z = (uint)f2bf(a1.x) | ((uint)f2bf(a1.y) << 16);
        ua.w = (uint)f2bf(a1.z) | ((uint)f2bf(a1.w) << 16);
        *(uint4*)&As[sr][sp] = ua;
        // stage B: WT bf16 direct
        uint4 ub = *(const uint4*)(WT + (size_t)(j0 + sr) * HID + k0 + sp);
        *(uint4*)&Bs[sr][sp] = ub;
        __syncthreads();

        bf16x8 af = *(const bf16x8*)&As[16 * w + cl][ac];
        bf16x8 b0 = *(const bf16x8*)&Bs[ 0 + cl][ac];
        bf16x8 b1 = *(const bf16x8*)&Bs[16 + cl][ac];
        bf16x8 b2 = *(const bf16x8*)&Bs[32 + cl][ac];
        bf16x8 b3 = *(const bf16x8*)&Bs[48 + cl][ac];
        acc0 = __builtin_amdgcn_mfma_f32_16x16x32_bf16(af, b0, acc0, 0, 0, 0);
        acc1 = __builtin_amdgcn_mfma_f32_16x16x32_bf16(af, b1, acc1, 0, 0, 0);
        acc2 = __builtin_amdgcn_mfma_f32_16x16x32_bf16(af, b2, acc2, 0, 0, 0);
        acc3 = __builtin_amdgcn_mfma_f32_16x16x32_bf16(af, b3, acc3, 0, 0, 0);
        __syncthreads();
    }

    // epilogue: part[r] = sum_j tanh(hW[j] + T) * v[j] over this block's 64 j
    float part0 = 0.f, part1 = 0.f, part2 = 0.f, part3 = 0.f;
#pragma unroll
    for (int jt = 0; jt < 4; ++jt) {
        int j = j0 + jt * 16 + cl;
        float hwj = hW[j], vj = attn_v[j];
        f32x4 a = (jt == 0) ? acc0 : (jt == 1) ? acc1 : (jt == 2) ? acc2 : acc3;
        part0 += tanhf(hwj + a[0]) * vj;
        part1 += tanhf(hwj + a[1]) * vj;
        part2 += tanhf(hwj + a[2]) * vj;
        part3 += tanhf(hwj + a[3]) * vj;
    }
#pragma unroll
    for (int m = 1; m <= 8; m <<= 1) {
        part0 += __shfl_xor(part0, m);
        part1 += __shfl_xor(part1, m);
        part2 += __shfl_xor(part2, m);
        part3 += __shfl_xor(part3, m);
    }
    if (cl == 0) {
        int srow = s0 + 16 * w + 4 * kq;    // D row = 4*(lane>>4) + reg
        atomicAdd(&scores[srow + 0], part0);
        atomicAdd(&scores[srow + 1], part1);
        atomicAdd(&scores[srow + 2], part2);
        atomicAdd(&scores[srow + 3], part3);
    }
}

// ---------------------------------------------------------------------------
// K2: softmax over 2048 scores -> wts. One block, 1024 threads.
// ---------------------------------------------------------------------------
__global__ __launch_bounds__(1024) void k_softmax(const float* scores, float* wts) {
    __shared__ float red[16];
    int tid = threadIdx.x, wid = tid >> 6, lane = tid & 63;
    float a = scores[tid], b = scores[tid + 1024];
    float m = fmaxf(a, b);
    for (int off = 32; off; off >>= 1) m = fmaxf(m, __shfl_xor(m, off));
    if (lane == 0) red[wid] = m;
    __syncthreads();
    float M = red[0];
#pragma unroll
    for (int q = 1; q < 16; ++q) M = fmaxf(M, red[q]);
    __syncthreads();
    float ea = expf(a - M), eb = expf(b - M);
    float s = ea + eb;
    for (int off = 32; off; off >>= 1) s += __shfl_xor(s, off);
    if (lane == 0) red[wid] = s;
    __syncthreads();
    float S = 0.f;
#pragma unroll
    for (int q = 0; q < 16; ++q) S += red[q];
    float inv = 1.f / S;
    wts[tid] = ea * inv;
    wts[tid + 1024] = eb * inv;
}

// ---------------------------------------------------------------------------
// K3: context[j] = sum_s wts[s]*enc[s][j] -> x[1024+j] (atomic partials)
// ---------------------------------------------------------------------------
__global__ __launch_bounds__(256) void k_context(const float* __restrict__ enc,
                                                 const float* __restrict__ wts,
                                                 float* x) {
    int b = blockIdx.x;
    int j0 = threadIdx.x * 4;
    float4 acc = {0.f, 0.f, 0.f, 0.f};
    for (int s = b * 32; s < b * 32 + 32; ++s) {
        float wv = wts[s];                                      // uniform
        float4 e = *(const float4*)(enc + (size_t)s * HID + j0);
        acc.x += wv * e.x; acc.y += wv * e.y; acc.z += wv * e.z; acc.w += wv * e.w;
    }
    atomicAdd(&x[1024 + j0 + 0], acc.x);
    atomicAdd(&x[1024 + j0 + 1], acc.y);
    atomicAdd(&x[1024 + j0 + 2], acc.z);
    atomicAdd(&x[1024 + j0 + 3], acc.w);
}

// ---------------------------------------------------------------------------
// K4: gi = W_ih @ x + b_ih. 1536 blocks, 2 rows/block, 2 waves per row.
// ---------------------------------------------------------------------------
__global__ __launch_bounds__(256) void k_gi(const float* __restrict__ W_ih,
                                            const float* __restrict__ b_ih,
                                            const float* __restrict__ x, float* gi) {
    __shared__ float red[4];
    int b = blockIdx.x;
    int wid = threadIdx.x >> 6, lane = threadIdx.x & 63;
    int row = b * 2 + (wid >> 1);
    int half = wid & 1;
    const float* wr = W_ih + (size_t)row * 2048 + half * 1024;
    const float* xr = x + half * 1024;
    float acc = 0.f;
#pragma unroll
    for (int it = 0; it < 4; ++it) {
        float4 wv = *(const float4*)(wr + it * 256 + lane * 4);
        float4 xv = *(const float4*)(xr + it * 256 + lane * 4);
        acc += wv.x * xv.x + wv.y * xv.y + wv.z * xv.z + wv.w * xv.w;
    }
    for (int off = 32; off; off >>= 1) acc += __shfl_down(acc, off);
    if (lane == 0) red[wid] = acc;
    __syncthreads();
    if (threadIdx.x < 2) {
        int r = b * 2 + threadIdx.x;
        gi[r] = red[threadIdx.x * 2] + red[threadIdx.x * 2 + 1] + b_ih[r];
    }
}

// ---------------------------------------------------------------------------
// K5: GRU gate math -> h_new
// ---------------------------------------------------------------------------
__global__ __launch_bounds__(256) void k_gru(const float* gi, const float* gh,
                                             const float* hidden, float* hn,
                                             float* out) {
    int i = blockIdx.x * 256 + threadIdx.x;
    float r = 1.f / (1.f + expf(-(gi[i] + gh[i])));
    float z = 1.f / (1.f + expf(-(gi[1024 + i] + gh[1024 + i])));
    float n = tanhf(gi[2048 + i] + r * gh[2048 + i]);
    float h = (1.f - z) * n + z * hidden[i];
    hn[i] = h;
    out[VOCAB + i] = h;
}

// ---------------------------------------------------------------------------
// K6: logits = out_W @ h_new + out_b; fused per-block (max, sum-exp) partials.
// ---------------------------------------------------------------------------
__global__ __launch_bounds__(256) void k_logits(const float* __restrict__ out_W,
                                                const float* __restrict__ out_b,
                                                const float* __restrict__ hn,
                                                float* logits, float* pm, float* psum) {
    __shared__ float lg[4];
    int b = blockIdx.x;
    int wid = threadIdx.x >> 6, lane = threadIdx.x & 63;
    int row = b * 4 + wid;
    float logit = -INFINITY;
    if (row < VOCAB) {
        const float* wr = out_W + (size_t)row * HID;
        float acc = 0.f;
#pragma unroll
        for (int it = 0; it < 4; ++it) {
            float4 wv = *(const float4*)(wr + it * 256 + lane * 4);
            float4 hv = *(const float4*)(hn + it * 256 + lane * 4);
            acc += wv.x * hv.x + wv.y * hv.y + wv.z * hv.z + wv.w * hv.w;
        }
        for (int off = 32; off; off >>= 1) acc += __shfl_down(acc, off);
        if (lane == 0) {
            logit = acc + out_b[row];
            logits[row] = logit;
        }
    }
    if (lane == 0) lg[wid] = logit;
    __syncthreads();
    if (threadIdx.x == 0) {
        float m = fmaxf(fmaxf(lg[0], lg[1]), fmaxf(lg[2], lg[3]));
        float s = 0.f;
#pragma unroll
        for (int q = 0; q < 4; ++q)
            if (lg[q] != -INFINITY) s += expf(lg[q] - m);
        pm[b] = m;
        psum[b] = s;
    }
}

// ---------------------------------------------------------------------------
// K7: combine per-block partials -> L = max + log(sum exp)
// ---------------------------------------------------------------------------
__global__ __launch_bounds__(256) void k_combine(const float* pm, const float* psum,
                                                 int n, float* Lval) {
    __shared__ float rm[4], rs[4];
    int tid = threadIdx.x, wid = tid >> 6, lane = tid & 63;
    float m = -INFINITY, s = 0.f;
    for (int i = tid; i < n; i += 256) {
        float bm = pm[i], bs = psum[i];
        float M = fmaxf(m, bm);
        s = s * expf(m - M) + bs * expf(bm - M);
        m = M;
    }
    for (int off = 32; off; off >>= 1) {
        float om = __shfl_xor(m, off), os = __shfl_xor(s, off);
        float M = fmaxf(m, om);
        s = s * expf(m - M) + os * expf(om - M);
        m = M;
    }
    if (lane == 0) { rm[wid] = m; rs[wid] = s; }
    __syncthreads();
    if (tid == 0) {
        float M = fmaxf(fmaxf(rm[0], rm[1]), fmaxf(rm[2], rm[3]));
        float S = rs[0] * expf(rm[0] - M) + rs[1] * expf(rm[1] - M)
                + rs[2] * expf(rm[2] - M) + rs[3] * expf(rm[3] - M);
        Lval[0] = M + logf(S);
    }
}

// ---------------------------------------------------------------------------
// K8: out[i] = logits[i] - L
// ---------------------------------------------------------------------------
__global__ __launch_bounds__(256) void k_final(const float* logits, const float* Lval,
                                               float* out) {
    int i = blockIdx.x * 256 + threadIdx.x;
    if (i < VOCAB) out[i] = logits[i] - Lval[0];
}

extern "C" void kernel_launch(void* const* d_in, const int* in_sizes, int n_in,
                              void* d_out, int out_size, void* d_ws, size_t ws_size,
                              hipStream_t stream) {
    (void)in_sizes; (void)n_in; (void)out_size; (void)ws_size;
    const int*   tok    = (const int*)d_in[0];
    const float* hidden = (const float*)d_in[1];
    const float* enc    = (const float*)d_in[2];
    const float* emb    = (const float*)d_in[3];
    const float* attn_W = (const float*)d_in[4];
    const float* attn_v = (const float*)d_in[5];
    const float* W_ih   = (const float*)d_in[6];
    const float* b_ih   = (const float*)d_in[7];
    const float* W_hh   = (const float*)d_in[8];
    const float* b_hh   = (const float*)d_in[9];
    const float* out_W  = (const float*)d_in[10];
    const float* out_b  = (const float*)d_in[11];
    float* out = (float*)d_out;
    float* ws  = (float*)d_ws;

    // workspace layout (floats)
    float* hW     = ws + 0;       // 1024
    float* gh     = ws + 1024;    // 3072
    float* gi     = ws + 4096;    // 3072
    float* x      = ws + 7168;    // 2048 (embedded | context)
    float* scores = ws + 9216;    // 2048
    float* wts    = ws + 11264;   // 2048
    float* hn     = ws + 13312;   // 1024
    float* logits = ws + 14336;   // 50257 (pad)
    float* pm     = ws + 64600;   // 12565 (pad)
    float* psum   = ws + 77168;   // 12565 (pad)
    float* Lval   = ws + 89736;   // 1
    ushort_t* WT  = (ushort_t*)(ws + 90112);  // 1024x1024 bf16 = 2 MB

    const int NLOGB = (VOCAB + 3) / 4;  // 12565

    k_init   <<<1, 256, 0, stream>>>(tok, emb, x, hW, scores);
    k_hw     <<<64, 256, 0, stream>>>(hidden, attn_W, hW);
    k_gh     <<<768, 256, 0, stream>>>(hidden, W_hh, b_hh, gh);
    k_transW <<<256, 256, 0, stream>>>(attn_W, WT);
    k_gemm   <<<512, 256, 0, stream>>>(enc, WT, hW, attn_v, scores);
    k_softmax<<<1, 1024, 0, stream>>>(scores, wts);
    k_context<<<64, 256, 0, stream>>>(enc, wts, x);
    k_gi     <<<1536, 256, 0, stream>>>(W_ih, b_ih, x, gi);
    k_gru    <<<4, 256, 0, stream>>>(gi, gh, hidden, hn, out);
    k_logits <<<NLOGB, 256, 0, stream>>>(out_W, out_b, hn, logits, pm, psum);
    k_combine<<<1, 256, 0, stream>>>(pm, psum, NLOGB, Lval);
    k_final  <<<(VOCAB + 255) / 256, 256, 0, stream>>>(logits, Lval, out);
}